// Round 6
// baseline (104.999 us; speedup 1.0000x reference)
//
#include <hip/hip_runtime.h>
#include <hip/hip_bf16.h>

#define S_DIM 1024
#define B_DIM 64
#define A_DIM 1024

// K2 = 2*log2(e): tanh(x) = 1 - 2/(exp2(K2*x)+1)
#define K2_CONST 2.8853900817779268f

#define K_TILE 64
#define KSPLIT 16
#define A_TILE 64
#define SSPLIT 32
#define S_CHUNK 32

typedef float f4 __attribute__((ext_vector_type(4)));

__device__ __forceinline__ float fast_exp2(float x) { return __builtin_amdgcn_exp2f(x); }
__device__ __forceinline__ float fast_rcp(float x)  { return __builtin_amdgcn_rcpf(x); }

// ---------------------------------------------------------------------------
// Kernel 1: split-K GEMM partials   part[kz][b][a] = sum_{k in chunk} s_tm1[b,k]*sa_w[a,k]
// ---------------------------------------------------------------------------
__global__ __launch_bounds__(256) void gemm_partial_kernel(
    const float* __restrict__ s_tm1,   // [B][1024]
    const float* __restrict__ sa_w,    // [1024][1024]
    float* __restrict__ part)          // [KSPLIT][B][1024]
{
    __shared__ float sW[K_TILE][68];   // [k][a_local]
    __shared__ float sS[K_TILE][68];   // [k][b]
    const int a0 = blockIdx.x * A_TILE;
    const int k0 = blockIdx.y * K_TILE;
    const int t  = threadIdx.x;

    #pragma unroll
    for (int i = 0; i < 4; ++i) {
        int idx = t + 256 * i;
        int row = idx >> 4;
        int c4  = (idx & 15) * 4;
        f4 v = __builtin_nontemporal_load((const f4*)(sa_w + (size_t)(a0 + row) * 1024 + k0 + c4));
        sW[c4 + 0][row] = v.x; sW[c4 + 1][row] = v.y;
        sW[c4 + 2][row] = v.z; sW[c4 + 3][row] = v.w;
        f4 u = *(const f4*)(s_tm1 + (size_t)row * 1024 + k0 + c4);
        sS[c4 + 0][row] = u.x; sS[c4 + 1][row] = u.y;
        sS[c4 + 2][row] = u.z; sS[c4 + 3][row] = u.w;
    }
    __syncthreads();

    const int ta = (t & 15) * 4;       // a_local base
    const int tb = (t >> 4) * 4;       // b base
    float acc[4][4] = {};
    #pragma unroll 8
    for (int k = 0; k < K_TILE; ++k) {
        f4 wa = *(const f4*)&sW[k][ta];
        f4 sb = *(const f4*)&sS[k][tb];
        float wv[4] = {wa.x, wa.y, wa.z, wa.w};
        float sv[4] = {sb.x, sb.y, sb.z, sb.w};
        #pragma unroll
        for (int i = 0; i < 4; ++i)
            #pragma unroll
            for (int j = 0; j < 4; ++j)
                acc[i][j] = fmaf(wv[i], sv[j], acc[i][j]);
    }

    float* outp = part + (size_t)blockIdx.y * (B_DIM * 1024);
    #pragma unroll
    for (int j = 0; j < 4; ++j) {
        f4 v = {acc[0][j], acc[1][j], acc[2][j], acc[3][j]};
        *(f4*)(outp + (size_t)(tb + j) * 1024 + a0 + ta) = v;
    }
}

// ---------------------------------------------------------------------------
// Kernel 1b: ksa[b][a] = K2 * (sa_b[a] + sum_kz part[kz][b][a])
// ---------------------------------------------------------------------------
__global__ __launch_bounds__(256) void gemm_reduce_kernel(
    const float* __restrict__ part, const float* __restrict__ sa_b,
    float* __restrict__ ksa)           // [B][1024]
{
    int idx = blockIdx.x * 256 + threadIdx.x;   // over [B][1024]
    int a = idx & 1023;
    float s = sa_b[a];
    #pragma unroll
    for (int kz = 0; kz < KSPLIT; ++kz)
        s += part[(size_t)kz * 65536 + idx];
    ksa[idx] = K2_CONST * s;
}

// ---------------------------------------------------------------------------
// Kernel 2 (fused): per (b, s-chunk of 32) block, wave w handles rows
// {w, w+4, ..., w+28}. Per row: reduce uh row -> ex (butterfly, all lanes),
// immediately FMA the matching xs_h row into private accumulators.
// 2048 blocks -> 8 blocks/CU -> ~32 waves/CU for memory-level parallelism.
// ---------------------------------------------------------------------------
__global__ __launch_bounds__(256) void fused_kernel(
    const float* __restrict__ uh,      // [S][B][1024]
    const float* __restrict__ xs_h,    // [S][B][1024]
    const float* __restrict__ ksa,     // [B][1024] (pre-scaled by K2)
    const float* __restrict__ a1_w,    // [1024]
    const float* __restrict__ xs_mask, // [S][B]
    float* __restrict__ ex_buf,        // [S][B] (unnormalized masked ex)
    float* __restrict__ psum,          // [SSPLIT][B]
    float* __restrict__ part)          // [SSPLIT][B][1024]
{
    const int b    = blockIdx.x;
    const int sz   = blockIdx.y;
    const int s0   = sz * S_CHUNK;
    const int t    = threadIdx.x;
    const int lane = t & 63;
    const int w    = t >> 6;

    __shared__ float s_ex[S_CHUNK];
    __shared__ float s_mask[S_CHUNK];
    __shared__ f4 s_red[4][256];

    if (t < S_CHUNK) s_mask[t] = xs_mask[(size_t)(s0 + t) * B_DIM + b];

    // block-invariant fragments -> registers
    const f4* sap = (const f4*)(ksa + (size_t)b * 1024);
    const f4* awp = (const f4*)a1_w;
    f4 sv[4], aw[4];
    #pragma unroll
    for (int j = 0; j < 4; ++j) { sv[j] = sap[lane + 64 * j]; aw[j] = awp[lane + 64 * j]; }

    __syncthreads();

    f4 acc4[4];
    #pragma unroll
    for (int j = 0; j < 4; ++j) { acc4[j].x = 0.f; acc4[j].y = 0.f; acc4[j].z = 0.f; acc4[j].w = 0.f; }

    // wave w handles rows {w, w+4, ..., w+28}
    #pragma unroll 2
    for (int k = 0; k < S_CHUNK / 4; ++k) {
        const int i = w + 4 * k;
        const size_t rowoff = ((size_t)(s0 + i) * B_DIM + b) * 1024;
        const f4* uhp = (const f4*)(uh + rowoff);
        const f4* xsp = (const f4*)(xs_h + rowoff);

        f4 xv[4];
        #pragma unroll
        for (int j = 0; j < 4; ++j) xv[j] = xsp[lane + 64 * j];   // L3-resident

        float acc = 0.f;
        #pragma unroll
        for (int j = 0; j < 4; ++j) {
            f4 u = __builtin_nontemporal_load(&uhp[lane + 64 * j]); // NT: keep xs_h in L3
            float t0 = fast_exp2(fmaf(K2_CONST, u.x, sv[j].x));
            float t1 = fast_exp2(fmaf(K2_CONST, u.y, sv[j].y));
            float t2 = fast_exp2(fmaf(K2_CONST, u.z, sv[j].z));
            float t3 = fast_exp2(fmaf(K2_CONST, u.w, sv[j].w));
            acc = fmaf(aw[j].x, fast_rcp(1.0f + t0), acc);
            acc = fmaf(aw[j].y, fast_rcp(1.0f + t1), acc);
            acc = fmaf(aw[j].z, fast_rcp(1.0f + t2), acc);
            acc = fmaf(aw[j].w, fast_rcp(1.0f + t3), acc);
        }
        #pragma unroll
        for (int off = 32; off; off >>= 1) acc += __shfl_xor(acc, off);  // all lanes get sum

        float ex = fast_exp2(-K2_CONST * acc) * s_mask[i];
        if (lane == 0) s_ex[i] = ex;

        #pragma unroll
        for (int j = 0; j < 4; ++j) {
            acc4[j].x = fmaf(ex, xv[j].x, acc4[j].x);
            acc4[j].y = fmaf(ex, xv[j].y, acc4[j].y);
            acc4[j].z = fmaf(ex, xv[j].z, acc4[j].z);
            acc4[j].w = fmaf(ex, xv[j].w, acc4[j].w);
        }
    }

    // combine 4 waves' partials
    #pragma unroll
    for (int j = 0; j < 4; ++j) s_red[w][lane + 64 * j] = acc4[j];
    __syncthreads();

    f4 r = s_red[0][t];
    #pragma unroll
    for (int ww = 1; ww < 4; ++ww) {
        f4 q = s_red[ww][t];
        r.x += q.x; r.y += q.y; r.z += q.z; r.w += q.w;
    }
    ((f4*)part)[((size_t)sz * B_DIM + b) * 256 + t] = r;

    if (t < S_CHUNK)
        ex_buf[(size_t)(s0 + t) * B_DIM + b] = s_ex[t];

    if (w == 0) {
        float v = (lane < S_CHUNK) ? s_ex[lane] : 0.f;
        #pragma unroll
        for (int off = 32; off; off >>= 1) v += __shfl_xor(v, off);
        if (lane == 0) psum[sz * B_DIM + b] = v;
    }
}

// ---------------------------------------------------------------------------
// Kernel 3 (finalize): blocks 0..255: eij = ex_buf * inv_sum[b]
//                      blocks 256..511: attend = (sum_sz part) * inv_sum[b]
// ---------------------------------------------------------------------------
__global__ __launch_bounds__(256) void finalize_kernel(
    const float* __restrict__ ex_buf, const float* __restrict__ part,
    const float* __restrict__ psum,
    float* __restrict__ eij_out, float* __restrict__ att_out)
{
    const int blk = blockIdx.x;
    const int t = threadIdx.x;
    if (blk < 256) {
        int idx = blk * 256 + t;           // over [S][B]
        int b = idx & 63;
        float ssum = 0.f;
        #pragma unroll
        for (int sz = 0; sz < SSPLIT; ++sz) ssum += psum[sz * B_DIM + b];
        eij_out[idx] = ex_buf[idx] * (1.0f / ssum);
    } else {
        int idx = (blk - 256) * 256 + t;   // over [B][1024]
        int b = idx >> 10;
        float ssum = 0.f;
        #pragma unroll
        for (int sz = 0; sz < SSPLIT; ++sz) ssum += psum[sz * B_DIM + b];
        float acc = 0.f;
        #pragma unroll
        for (int sz = 0; sz < SSPLIT; ++sz) acc += part[(size_t)sz * 65536 + idx];
        att_out[idx] = acc * (1.0f / ssum);
    }
}

// ---------------------------------------------------------------------------
extern "C" void kernel_launch(void* const* d_in, const int* in_sizes, int n_in,
                              void* d_out, int out_size, void* d_ws, size_t ws_size,
                              hipStream_t stream) {
    const float* s_tm1   = (const float*)d_in[0];  // [64][1024]
    const float* xs_h    = (const float*)d_in[1];  // [1024][64][1024]
    const float* uh      = (const float*)d_in[2];  // [1024][64][1024]
    const float* xs_mask = (const float*)d_in[3];  // [1024][64]
    const float* sa_w    = (const float*)d_in[4];  // [1024][1024]
    const float* sa_b    = (const float*)d_in[5];  // [1024]
    const float* a1_w    = (const float*)d_in[6];  // [1][1024]
    // d_in[7] = a1_b: global constant shift -> cancels in softmax.

    float* eij_out = (float*)d_out;                 // [S][B]
    float* att_out = (float*)d_out + S_DIM * B_DIM; // [B][1024]

    float* part_gemm = (float*)d_ws;                               // 16*64*1024
    float* ksa       = part_gemm + (size_t)KSPLIT * B_DIM * 1024;  // 64*1024
    float* ex_buf    = ksa + 65536;                                // [S][B]
    float* part_att  = ex_buf + 65536;                             // 32*64*1024
    float* psum      = part_att + (size_t)SSPLIT * B_DIM * 1024;   // 32*64

    gemm_partial_kernel<<<dim3(A_DIM / A_TILE, KSPLIT), 256, 0, stream>>>(s_tm1, sa_w, part_gemm);
    gemm_reduce_kernel<<<65536 / 256, 256, 0, stream>>>(part_gemm, sa_b, ksa);
    fused_kernel<<<dim3(B_DIM, SSPLIT), 256, 0, stream>>>(uh, xs_h, ksa, a1_w, xs_mask,
                                                          ex_buf, psum, part_att);
    finalize_kernel<<<512, 256, 0, stream>>>(ex_buf, part_att, psum, eij_out, att_out);
}

// Round 7
// 96.473 us; speedup vs baseline: 1.0884x; 1.0884x over previous
//
#include <hip/hip_runtime.h>
#include <hip/hip_bf16.h>

#define S_DIM 1024
#define B_DIM 64
#define A_DIM 1024

// K2 = 2*log2(e): tanh(x) = 1 - 2/(exp2(K2*x)+1)
#define K2_CONST 2.8853900817779268f

#define K_TILE 64
#define KSPLIT 16
#define A_TILE 64
#define SSPLIT 16
#define S_CHUNK 64

typedef float f4 __attribute__((ext_vector_type(4)));

__device__ __forceinline__ float fast_exp2(float x) { return __builtin_amdgcn_exp2f(x); }
__device__ __forceinline__ float fast_rcp(float x)  { return __builtin_amdgcn_rcpf(x); }

// ---------------------------------------------------------------------------
// Kernel 1: split-K GEMM partials   part[kz][b][a] = sum_{k in chunk} s_tm1[b,k]*sa_w[a,k]
// ---------------------------------------------------------------------------
__global__ __launch_bounds__(256) void gemm_partial_kernel(
    const float* __restrict__ s_tm1,   // [B][1024]
    const float* __restrict__ sa_w,    // [1024][1024]
    float* __restrict__ part)          // [KSPLIT][B][1024]
{
    __shared__ float sW[K_TILE][68];   // [k][a_local]
    __shared__ float sS[K_TILE][68];   // [k][b]
    const int a0 = blockIdx.x * A_TILE;
    const int k0 = blockIdx.y * K_TILE;
    const int t  = threadIdx.x;

    #pragma unroll
    for (int i = 0; i < 4; ++i) {
        int idx = t + 256 * i;
        int row = idx >> 4;
        int c4  = (idx & 15) * 4;
        f4 v = __builtin_nontemporal_load((const f4*)(sa_w + (size_t)(a0 + row) * 1024 + k0 + c4));
        sW[c4 + 0][row] = v.x; sW[c4 + 1][row] = v.y;
        sW[c4 + 2][row] = v.z; sW[c4 + 3][row] = v.w;
        f4 u = *(const f4*)(s_tm1 + (size_t)row * 1024 + k0 + c4);
        sS[c4 + 0][row] = u.x; sS[c4 + 1][row] = u.y;
        sS[c4 + 2][row] = u.z; sS[c4 + 3][row] = u.w;
    }
    __syncthreads();

    const int ta = (t & 15) * 4;       // a_local base
    const int tb = (t >> 4) * 4;       // b base
    float acc[4][4] = {};
    #pragma unroll 8
    for (int k = 0; k < K_TILE; ++k) {
        f4 wa = *(const f4*)&sW[k][ta];
        f4 sb = *(const f4*)&sS[k][tb];
        float wv[4] = {wa.x, wa.y, wa.z, wa.w};
        float sv[4] = {sb.x, sb.y, sb.z, sb.w};
        #pragma unroll
        for (int i = 0; i < 4; ++i)
            #pragma unroll
            for (int j = 0; j < 4; ++j)
                acc[i][j] = fmaf(wv[i], sv[j], acc[i][j]);
    }

    float* outp = part + (size_t)blockIdx.y * (B_DIM * 1024);
    #pragma unroll
    for (int j = 0; j < 4; ++j) {
        f4 v = {acc[0][j], acc[1][j], acc[2][j], acc[3][j]};
        *(f4*)(outp + (size_t)(tb + j) * 1024 + a0 + ta) = v;
    }
}

// ---------------------------------------------------------------------------
// Kernel 1b: ksa[b][a] = K2 * (sa_b[a] + sum_kz part[kz][b][a])
// ---------------------------------------------------------------------------
__global__ __launch_bounds__(256) void gemm_reduce_kernel(
    const float* __restrict__ part, const float* __restrict__ sa_b,
    float* __restrict__ ksa)           // [B][1024]
{
    int idx = blockIdx.x * 256 + threadIdx.x;   // over [B][1024]
    int a = idx & 1023;
    float s = sa_b[a];
    #pragma unroll
    for (int kz = 0; kz < KSPLIT; ++kz)
        s += part[(size_t)kz * 65536 + idx];
    ksa[idx] = K2_CONST * s;
}

// ---------------------------------------------------------------------------
// Kernel 2 (fused, 2-row unroll-jam): wave w handles row pairs
// (w+8k, w+8k+4), k=0..7. All 16 loads of a pair are issued before either
// dependency chain; the two exp/rcp chains are independent -> 2x VALU ILP
// and 8 KB/wave in flight. Both results are consumed, so the compiler
// cannot collapse the overlap (unlike a copy-rotated prefetch pipeline).
// ---------------------------------------------------------------------------
__global__ __launch_bounds__(256) void fused_kernel(
    const float* __restrict__ uh,      // [S][B][1024]
    const float* __restrict__ xs_h,    // [S][B][1024]
    const float* __restrict__ ksa,     // [B][1024] (pre-scaled by K2)
    const float* __restrict__ a1_w,    // [1024]
    const float* __restrict__ xs_mask, // [S][B]
    float* __restrict__ ex_buf,        // [S][B] (unnormalized masked ex)
    float* __restrict__ psum,          // [SSPLIT][B]
    float* __restrict__ part)          // [SSPLIT][B][1024]
{
    const int b    = blockIdx.x;
    const int sz   = blockIdx.y;
    const int s0   = sz * S_CHUNK;
    const int t    = threadIdx.x;
    const int lane = t & 63;
    const int w    = t >> 6;

    __shared__ float s_ex[S_CHUNK];
    __shared__ float s_mask[S_CHUNK];
    __shared__ f4 s_red[4][256];

    if (t < S_CHUNK) s_mask[t] = xs_mask[(size_t)(s0 + t) * B_DIM + b];

    // block-invariant fragments -> registers
    const f4* sap = (const f4*)(ksa + (size_t)b * 1024);
    const f4* awp = (const f4*)a1_w;
    f4 sv[4], aw[4];
    #pragma unroll
    for (int j = 0; j < 4; ++j) { sv[j] = sap[lane + 64 * j]; aw[j] = awp[lane + 64 * j]; }

    __syncthreads();

    f4 acc4[4];
    #pragma unroll
    for (int j = 0; j < 4; ++j) { acc4[j].x = 0.f; acc4[j].y = 0.f; acc4[j].z = 0.f; acc4[j].w = 0.f; }

    #pragma unroll 1
    for (int k = 0; k < S_CHUNK / 8; ++k) {
        const int i0 = w + 8 * k;
        const int i1 = i0 + 4;
        const size_t ro0 = ((size_t)(s0 + i0) * B_DIM + b) * 1024;
        const size_t ro1 = ((size_t)(s0 + i1) * B_DIM + b) * 1024;
        const f4* up0 = (const f4*)(uh + ro0);
        const f4* up1 = (const f4*)(uh + ro1);
        const f4* xp0 = (const f4*)(xs_h + ro0);
        const f4* xp1 = (const f4*)(xs_h + ro1);

        f4 u0[4], u1[4], x0[4], x1[4];
        #pragma unroll
        for (int j = 0; j < 4; ++j) u0[j] = __builtin_nontemporal_load(&up0[lane + 64 * j]);
        #pragma unroll
        for (int j = 0; j < 4; ++j) u1[j] = __builtin_nontemporal_load(&up1[lane + 64 * j]);
        #pragma unroll
        for (int j = 0; j < 4; ++j) x0[j] = xp0[lane + 64 * j];   // L3-resident
        #pragma unroll
        for (int j = 0; j < 4; ++j) x1[j] = xp1[lane + 64 * j];

        float a0 = 0.f, a1 = 0.f;
        #pragma unroll
        for (int j = 0; j < 4; ++j) {
            float p00 = fast_exp2(fmaf(K2_CONST, u0[j].x, sv[j].x));
            float p10 = fast_exp2(fmaf(K2_CONST, u1[j].x, sv[j].x));
            float p01 = fast_exp2(fmaf(K2_CONST, u0[j].y, sv[j].y));
            float p11 = fast_exp2(fmaf(K2_CONST, u1[j].y, sv[j].y));
            float p02 = fast_exp2(fmaf(K2_CONST, u0[j].z, sv[j].z));
            float p12 = fast_exp2(fmaf(K2_CONST, u1[j].z, sv[j].z));
            float p03 = fast_exp2(fmaf(K2_CONST, u0[j].w, sv[j].w));
            float p13 = fast_exp2(fmaf(K2_CONST, u1[j].w, sv[j].w));
            a0 = fmaf(aw[j].x, fast_rcp(1.0f + p00), a0);
            a1 = fmaf(aw[j].x, fast_rcp(1.0f + p10), a1);
            a0 = fmaf(aw[j].y, fast_rcp(1.0f + p01), a0);
            a1 = fmaf(aw[j].y, fast_rcp(1.0f + p11), a1);
            a0 = fmaf(aw[j].z, fast_rcp(1.0f + p02), a0);
            a1 = fmaf(aw[j].z, fast_rcp(1.0f + p12), a1);
            a0 = fmaf(aw[j].w, fast_rcp(1.0f + p03), a0);
            a1 = fmaf(aw[j].w, fast_rcp(1.0f + p13), a1);
        }
        #pragma unroll
        for (int off = 32; off; off >>= 1) {
            a0 += __shfl_xor(a0, off);
            a1 += __shfl_xor(a1, off);
        }

        float ex0 = fast_exp2(-K2_CONST * a0) * s_mask[i0];
        float ex1 = fast_exp2(-K2_CONST * a1) * s_mask[i1];
        if (lane == 0) { s_ex[i0] = ex0; s_ex[i1] = ex1; }

        #pragma unroll
        for (int j = 0; j < 4; ++j) {
            acc4[j].x = fmaf(ex0, x0[j].x, fmaf(ex1, x1[j].x, acc4[j].x));
            acc4[j].y = fmaf(ex0, x0[j].y, fmaf(ex1, x1[j].y, acc4[j].y));
            acc4[j].z = fmaf(ex0, x0[j].z, fmaf(ex1, x1[j].z, acc4[j].z));
            acc4[j].w = fmaf(ex0, x0[j].w, fmaf(ex1, x1[j].w, acc4[j].w));
        }
    }

    // combine 4 waves' partials
    #pragma unroll
    for (int j = 0; j < 4; ++j) s_red[w][lane + 64 * j] = acc4[j];
    __syncthreads();

    f4 r = s_red[0][t];
    #pragma unroll
    for (int ww = 1; ww < 4; ++ww) {
        f4 q = s_red[ww][t];
        r.x += q.x; r.y += q.y; r.z += q.z; r.w += q.w;
    }
    ((f4*)part)[((size_t)sz * B_DIM + b) * 256 + t] = r;

    if (t < S_CHUNK)
        ex_buf[(size_t)(s0 + t) * B_DIM + b] = s_ex[t];

    if (w == 0) {
        float v = s_ex[lane];
        #pragma unroll
        for (int off = 32; off; off >>= 1) v += __shfl_xor(v, off);
        if (lane == 0) psum[sz * B_DIM + b] = v;
    }
}

// ---------------------------------------------------------------------------
// Kernel 3 (finalize): blocks 0..255: eij = ex_buf * inv_sum[b]
//                      blocks 256..511: attend = (sum_sz part) * inv_sum[b]
// ---------------------------------------------------------------------------
__global__ __launch_bounds__(256) void finalize_kernel(
    const float* __restrict__ ex_buf, const float* __restrict__ part,
    const float* __restrict__ psum,
    float* __restrict__ eij_out, float* __restrict__ att_out)
{
    const int blk = blockIdx.x;
    const int t = threadIdx.x;
    if (blk < 256) {
        int idx = blk * 256 + t;           // over [S][B]
        int b = idx & 63;
        float ssum = 0.f;
        #pragma unroll
        for (int sz = 0; sz < SSPLIT; ++sz) ssum += psum[sz * B_DIM + b];
        eij_out[idx] = ex_buf[idx] * (1.0f / ssum);
    } else {
        int idx = (blk - 256) * 256 + t;   // over [B][1024]
        int b = idx >> 10;
        float ssum = 0.f;
        #pragma unroll
        for (int sz = 0; sz < SSPLIT; ++sz) ssum += psum[sz * B_DIM + b];
        float acc = 0.f;
        #pragma unroll
        for (int sz = 0; sz < SSPLIT; ++sz) acc += part[(size_t)sz * 65536 + idx];
        att_out[idx] = acc * (1.0f / ssum);
    }
}

// ---------------------------------------------------------------------------
extern "C" void kernel_launch(void* const* d_in, const int* in_sizes, int n_in,
                              void* d_out, int out_size, void* d_ws, size_t ws_size,
                              hipStream_t stream) {
    const float* s_tm1   = (const float*)d_in[0];  // [64][1024]
    const float* xs_h    = (const float*)d_in[1];  // [1024][64][1024]
    const float* uh      = (const float*)d_in[2];  // [1024][64][1024]
    const float* xs_mask = (const float*)d_in[3];  // [1024][64]
    const float* sa_w    = (const float*)d_in[4];  // [1024][1024]
    const float* sa_b    = (const float*)d_in[5];  // [1024]
    const float* a1_w    = (const float*)d_in[6];  // [1][1024]
    // d_in[7] = a1_b: global constant shift -> cancels in softmax.

    float* eij_out = (float*)d_out;                 // [S][B]
    float* att_out = (float*)d_out + S_DIM * B_DIM; // [B][1024]

    float* part_gemm = (float*)d_ws;                               // 16*64*1024
    float* ksa       = part_gemm + (size_t)KSPLIT * B_DIM * 1024;  // 64*1024
    float* ex_buf    = ksa + 65536;                                // [S][B]
    float* part_att  = ex_buf + 65536;                             // 16*64*1024
    float* psum      = part_att + (size_t)SSPLIT * B_DIM * 1024;   // 16*64

    gemm_partial_kernel<<<dim3(A_DIM / A_TILE, KSPLIT), 256, 0, stream>>>(s_tm1, sa_w, part_gemm);
    gemm_reduce_kernel<<<65536 / 256, 256, 0, stream>>>(part_gemm, sa_b, ksa);
    fused_kernel<<<dim3(B_DIM, SSPLIT), 256, 0, stream>>>(uh, xs_h, ksa, a1_w, xs_mask,
                                                          ex_buf, psum, part_att);
    finalize_kernel<<<512, 256, 0, stream>>>(ex_buf, part_att, psum, eij_out, att_out);
}